// Round 20
// baseline (551.326 us; speedup 1.0000x reference)
//
#include <hip/hip_runtime.h>
#include <stdint.h>

typedef unsigned short u16;
typedef __attribute__((ext_vector_type(8))) short bf16x8;
typedef __attribute__((ext_vector_type(8))) unsigned short u16x8;
typedef __attribute__((ext_vector_type(4))) float f32x4;
typedef __attribute__((ext_vector_type(4))) unsigned short u16x4;

#define DIM 2048
#define HEADS 16
#define HEAD_DIM 128
#define HALF 64
#define LATENT 256
#define BATCH 2
#define SEQ 2048
#define TOK (BATCH*SEQ)

#if defined(__has_builtin)
#if __has_builtin(__builtin_amdgcn_exp2f)
#define EXP2F(x) __builtin_amdgcn_exp2f(x)
#endif
#endif
#ifndef EXP2F
#define EXP2F(x) exp2f(x)
#endif

#define SCALE_C 0.18033688011112042f   // (1/sqrt(64)) * log2(e), folded into Q

__device__ __forceinline__ u16 f2bf(float f) {
  uint32_t u = __float_as_uint(f);
  u += 0x7fff + ((u >> 16) & 1);   // round-to-nearest-even
  return (u16)(u >> 16);
}

__device__ __forceinline__ float bf2f(u16 h) {
  return __uint_as_float((uint32_t)h << 16);
}

__device__ __forceinline__ f32x4 mfma16(bf16x8 a, bf16x8 b, f32x4 c) {
  return __builtin_amdgcn_mfma_f32_16x16x32_bf16(a, b, c, 0, 0, 0);
}

__device__ __forceinline__ void async_copy16(const void* g, void* l) {
  __builtin_amdgcn_global_load_lds(
      (const __attribute__((address_space(1))) void*)g,
      (__attribute__((address_space(3))) void*)l, 16, 0, 0);
}

// ---------------- fused prep: 4 weight transposes + rope tables ----------------
__global__ void prep_k(const float* __restrict__ wq_d, const float* __restrict__ wkv_d,
                       const float* __restrict__ wq_u, const float* __restrict__ wk_u,
                       const float* __restrict__ wv_u, const float* __restrict__ wo,
                       u16* __restrict__ wdT, u16* __restrict__ wquT, u16* __restrict__ wkuT,
                       u16* __restrict__ wvuT, u16* __restrict__ woT,
                       float* __restrict__ ct, float* __restrict__ st) {
  __shared__ float tile[32][33];
  const int f = blockIdx.x;
  const int tx = threadIdx.x, ty = threadIdx.y;

  const float* in = nullptr;
  u16* out = nullptr;
  int N = 0, row_off = 0, out_ld = 0, bx = 0, by = 0;

  if (f < 1024) {
    int z = f >> 9, r = f & 511;
    bx = r & 7; by = r >> 3;
    in = z ? wkv_d : wq_d; out = wdT; row_off = z * 256; N = 256; out_ld = 2048;
  } else if (f < 1536) {
    int r = f - 1024; int z = r >> 8; r &= 255;
    bx = r & 31; by = r >> 5;
    in = z ? wk_u : wq_u; out = z ? wkuT : wquT; row_off = 0; N = 1024; out_ld = 256;
  } else if (f < 2048) {
    int r = f - 1536;
    bx = r & 63; by = r >> 6;
    in = wv_u; out = wvuT; row_off = 0; N = 2048; out_ld = 256;
  } else if (f < 6144) {
    int r = f - 2048;
    bx = r & 63; by = r >> 6;
    in = wo; out = woT; row_off = 0; N = 2048; out_ld = 2048;
  } else {
    int t = (f - 6144) * 256 + ty * 32 + tx;
    int i = t & 31, s = t >> 5;
    float invf = expf(-(float)i * 0.28782313662425575f);
    float a = (float)s * invf;
    ct[t] = cosf(a);
    st[t] = sinf(a);
    return;
  }
  int k0 = by * 32, n0 = bx * 32;
  #pragma unroll
  for (int j = 0; j < 32; j += 8)
    tile[ty + j][tx] = in[(size_t)(k0 + ty + j) * N + n0 + tx];
  __syncthreads();
  #pragma unroll
  for (int j = 0; j < 32; j += 8)
    out[(size_t)(n0 + ty + j + row_off) * out_ld + k0 + tx] = f2bf(tile[tx][ty + j]);
}

// ---------------- combine 4 bf16 split-K slabs (fp32 accumulate) ----------------
__global__ void combine_bf(const u16* __restrict__ p, u16* __restrict__ out,
                           int n8, size_t slab) {
  int t = blockIdx.x * 256 + threadIdx.x;
  if (t >= n8) return;
  size_t base = (size_t)t * 8;
  float a[8] = {};
  #pragma unroll
  for (int s = 0; s < 4; ++s) {
    u16x8 v = *(const u16x8*)&p[base + s * slab];
    #pragma unroll
    for (int e = 0; e < 8; ++e) a[e] += bf2f(v[e]);
  }
  u16x8 o;
  #pragma unroll
  for (int e = 0; e < 8; ++e) o[e] = f2bf(a[e]);
  *(u16x8*)&out[base] = o;
}

// ---------------- lat GEMM: A fp32 reg-staged, split-K4, bf16 partials out ----------------
__global__ __launch_bounds__(256)
void gemm_lat(const float* __restrict__ A, int lda, const u16* __restrict__ BT, int ldb,
              u16* __restrict__ Cv, int M, int N, int K) {
  __shared__ __align__(16) u16 As[128 * 32];
  __shared__ __align__(16) u16 Bs[128 * 32];
  const int tid = threadIdx.x;
  const int lane = tid & 63;
  const int wid = tid >> 6;
  const int z = blockIdx.z;
  int koff = z * K;
  const int nb = gridDim.x * gridDim.y;
  int f = blockIdx.x + gridDim.x * blockIdx.y;
  f = (f & 7) * (nb >> 3) + (f >> 3);
  const int m0 = (f / gridDim.x) * 128;
  const int n0 = (f % gridDim.x) * 128;
  const int wr = wid >> 1, wc = wid & 1;
  const int l15 = lane & 15, lg = lane >> 4;
  const int rA = lane >> 2;
  const int kqL = (lane & 3) * 8;
  const int kqS = ((((lane & 3) - ((lane >> 3) & 3)) & 3)) * 8;
  const int sWr = (((lane & 3) + ((lane >> 3) & 3)) & 3) * 8;
  const int rsw = (l15 >> 1) & 3;

  f32x4 acc[4][4] = {};
  const int nk = K / 32;
  for (int kt = 0; kt < nk; ++kt) {
    const int k0 = koff + kt * 32;
    #pragma unroll
    for (int c = 0; c < 2; ++c) {
      int ca = wid * 2 + c;
      const float* ga = A + (size_t)(m0 + ca * 16 + rA) * lda + k0 + kqL;
      float4 v0 = *(const float4*)ga;
      float4 v1 = *(const float4*)(ga + 4);
      union { u16 h[8]; bf16x8 v; } pk;
      pk.h[0] = f2bf(v0.x); pk.h[1] = f2bf(v0.y); pk.h[2] = f2bf(v0.z); pk.h[3] = f2bf(v0.w);
      pk.h[4] = f2bf(v1.x); pk.h[5] = f2bf(v1.y); pk.h[6] = f2bf(v1.z); pk.h[7] = f2bf(v1.w);
      *(bf16x8*)&As[ca * 512 + rA * 32 + sWr] = pk.v;
      const u16* gb = BT + (size_t)(n0 + ca * 16 + rA) * ldb + k0 + kqS;
      async_copy16(gb, &Bs[ca * 512]);
    }
    __syncthreads();
    bf16x8 af[4], bfr[4];
    const int slot = ((lg + rsw) & 3) * 8;
    #pragma unroll
    for (int i = 0; i < 4; ++i) {
      af[i]  = *(const bf16x8*)&As[(wr * 64 + i * 16 + l15) * 32 + slot];
      bfr[i] = *(const bf16x8*)&Bs[(wc * 64 + i * 16 + l15) * 32 + slot];
    }
    #pragma unroll
    for (int i = 0; i < 4; ++i)
      #pragma unroll
      for (int j = 0; j < 4; ++j)
        acc[i][j] = mfma16(af[i], bfr[j], acc[i][j]);
    __syncthreads();
  }
  #pragma unroll
  for (int i = 0; i < 4; ++i) {
    #pragma unroll
    for (int j = 0; j < 4; ++j) {
      int row = m0 + wr * 64 + i * 16 + lg * 4;
      int col = n0 + wc * 64 + j * 16 + l15;
      #pragma unroll
      for (int r = 0; r < 4; ++r)
        Cv[(size_t)z * M * N + (size_t)(row + r) * N + col] = f2bf(acc[i][j][r]);
    }
  }
}

// ---------------- wo GEMM: 3-buf counted-vmcnt pipeline ----------------
__global__ __launch_bounds__(256)
void gemm_wo(const u16* __restrict__ A, const u16* __restrict__ BT,
             float* __restrict__ C) {
  __shared__ __align__(16) u16 As[3][128 * 32];
  __shared__ __align__(16) u16 Bs[3][128 * 32];
  const int tid = threadIdx.x, lane = tid & 63, wid = tid >> 6;
  const int nb = gridDim.x * gridDim.y;          // 512
  int f = blockIdx.x + gridDim.x * blockIdx.y;
  f = (f & 7) * (nb >> 3) + (f >> 3);            // XCD swizzle
  const int m0 = (f / gridDim.x) * 128;
  const int n0 = (f % gridDim.x) * 128;
  const int wr = wid >> 1, wc = wid & 1;
  const int l15 = lane & 15, lg = lane >> 4;
  const int rA = lane >> 2;
  const int kqS = ((((lane & 3) - ((lane >> 3) & 3)) & 3)) * 8;
  const int rsw = (l15 >> 1) & 3;

  f32x4 acc[4][4] = {};

  auto stage = [&](u16* AsD, u16* BsD, int k0) {
    #pragma unroll
    for (int c = 0; c < 2; ++c) {
      int ca = wid * 2 + c;
      async_copy16(A + (size_t)(m0 + ca * 16 + rA) * DIM + k0 + kqS, AsD + ca * 512);
      async_copy16(BT + (size_t)(n0 + ca * 16 + rA) * DIM + k0 + kqS, BsD + ca * 512);
    }
  };
  auto compute = [&](const u16* AsP, const u16* BsP) {
    bf16x8 af[4], bfr[4];
    const int slot = ((lg + rsw) & 3) * 8;
    #pragma unroll
    for (int i = 0; i < 4; ++i) {
      af[i]  = *(const bf16x8*)&AsP[(wr * 64 + i * 16 + l15) * 32 + slot];
      bfr[i] = *(const bf16x8*)&BsP[(wc * 64 + i * 16 + l15) * 32 + slot];
    }
    __builtin_amdgcn_s_setprio(1);
    #pragma unroll
    for (int i = 0; i < 4; ++i)
      #pragma unroll
      for (int j = 0; j < 4; ++j)
        acc[i][j] = mfma16(af[i], bfr[j], acc[i][j]);
    __builtin_amdgcn_s_setprio(0);
  };

#define WAIT4 asm volatile("s_waitcnt vmcnt(4)" ::: "memory")
#define WAIT0 asm volatile("s_waitcnt vmcnt(0)" ::: "memory")
#define BAR   __builtin_amdgcn_s_barrier()

  stage(As[0], Bs[0], 0);
  stage(As[1], Bs[1], 32);
  WAIT4; BAR;
  int t = 0;
  for (int i = 0; i < 20; ++i) {                 // t = 0..59
    stage(As[2], Bs[2], (t + 2) * 32); compute(As[0], Bs[0]); WAIT4; BAR;
    stage(As[0], Bs[0], (t + 3) * 32); compute(As[1], Bs[1]); WAIT4; BAR;
    stage(As[1], Bs[1], (t + 4) * 32); compute(As[2], Bs[2]); WAIT4; BAR;
    t += 3;
  }
  stage(As[2], Bs[2], 62 * 32); compute(As[0], Bs[0]); WAIT4; BAR;
  stage(As[0], Bs[0], 63 * 32); compute(As[1], Bs[1]); WAIT4; BAR;
  compute(As[2], Bs[2]); WAIT0; BAR;
  compute(As[0], Bs[0]);

#undef WAIT4
#undef WAIT0
#undef BAR

  #pragma unroll
  for (int i = 0; i < 4; ++i) {
    #pragma unroll
    for (int j = 0; j < 4; ++j) {
      int row = m0 + wr * 64 + i * 16 + lg * 4;
      int col = n0 + wc * 64 + j * 16 + l15;
      #pragma unroll
      for (int r = 0; r < 4; ++r)
        C[(size_t)(row + r) * DIM + col] = acc[i][j][r];
    }
  }
}

// ---------------- merged up-proj, 3-buf counted-vmcnt pipeline (NT=8) ----------------
__global__ __launch_bounds__(256)
void upproj_k(const u16* __restrict__ A,
              const u16* __restrict__ wquT, const u16* __restrict__ wkuT,
              const u16* __restrict__ wvuT,
              u16* __restrict__ qb, u16* __restrict__ kb, u16* __restrict__ vT,
              const float* __restrict__ ct, const float* __restrict__ st) {
  __shared__ __align__(16) u16 As[3][128 * 32];
  __shared__ __align__(16) u16 Bs[3][128 * 32];
  const int tid = threadIdx.x;
  const int lane = tid & 63;
  const int wid = tid >> 6;
  int f = blockIdx.x;
  f = (f & 7) * 128 + (f >> 3);          // XCD swizzle over flat 1024
  const u16* BT; u16* out; int N, a_off, seg, r;
  if (f < 256)      { seg = 0; r = f;       BT = wquT; out = qb; N = 1024; a_off = 0; }
  else if (f < 512) { seg = 1; r = f - 256; BT = wkuT; out = kb; N = 1024; a_off = 256; }
  else              { seg = 2; r = f - 512; BT = wvuT; out = vT; N = 2048; a_off = 256; }
  const int gx = (seg == 2) ? 16 : 8;
  const int m0 = (r / gx) * 128;
  const int n0 = (r % gx) * 128;
  const int wr = wid >> 1, wc = wid & 1;
  const int l15 = lane & 15, lg = lane >> 4;
  const int rA = lane >> 2;
  const int kqS = ((((lane & 3) - ((lane >> 3) & 3)) & 3)) * 8;
  const int rsw = (l15 >> 1) & 3;

  f32x4 acc[4][4] = {};

  auto stage = [&](u16* AsD, u16* BsD, int k0) {
    #pragma unroll
    for (int c = 0; c < 2; ++c) {
      int ca = wid * 2 + c;
      async_copy16(A + (size_t)(m0 + ca * 16 + rA) * 512 + a_off + k0 + kqS, AsD + ca * 512);
      async_copy16(BT + (size_t)(n0 + ca * 16 + rA) * LATENT + k0 + kqS, BsD + ca * 512);
    }
  };
  auto compute = [&](const u16* AsP, const u16* BsP) {
    bf16x8 af[4], bfr[4];
    const int slot = ((lg + rsw) & 3) * 8;
    #pragma unroll
    for (int i = 0; i < 4; ++i) {
      af[i]  = *(const bf16x8*)&AsP[(wr * 64 + i * 16 + l15) * 32 + slot];
      bfr[i] = *(const bf16x8*)&BsP[(wc * 64 + i * 16 + l15) * 32 + slot];
    }
    __builtin_amdgcn_s_setprio(1);
    #pragma unroll
    for (int i = 0; i < 4; ++i)
      #pragma unroll
      for (int j = 0; j < 4; ++j)
        acc[i][j] = mfma16(af[i], bfr[j], acc[i][j]);
    __builtin_amdgcn_s_setprio(0);
  };

#define WAIT4 asm volatile("s_waitcnt vmcnt(4)" ::: "memory")
#define WAIT0 asm volatile("s_waitcnt vmcnt(0)" ::: "memory")
#define BAR   __builtin_amdgcn_s_barrier()

  // NT = 8 K-steps (K=256, BK=32)
  stage(As[0], Bs[0], 0);
  stage(As[1], Bs[1], 32);
  WAIT4; BAR;
  stage(As[2], Bs[2],  64); compute(As[0], Bs[0]); WAIT4; BAR;
  stage(As[0], Bs[0],  96); compute(As[1], Bs[1]); WAIT4; BAR;
  stage(As[1], Bs[1], 128); compute(As[2], Bs[2]); WAIT4; BAR;
  stage(As[2], Bs[2], 160); compute(As[0], Bs[0]); WAIT4; BAR;
  stage(As[0], Bs[0], 192); compute(As[1], Bs[1]); WAIT4; BAR;
  stage(As[1], Bs[1], 224); compute(As[2], Bs[2]); WAIT4; BAR;
  compute(As[0], Bs[0]); WAIT0; BAR;
  compute(As[1], Bs[1]);

#undef WAIT4
#undef WAIT0
#undef BAR

  if (seg <= 1) {
    const float qs = seg ? 1.0f : SCALE_C;
    #pragma unroll
    for (int i = 0; i < 4; ++i) {
      int rowb = m0 + wr * 64 + i * 16 + lg * 4;
      #pragma unroll
      for (int j = 0; j < 2; ++j) {
        int ii = j * 16 + l15;                 // 0..31 within head
        int colb = n0 + wc * 64;
        #pragma unroll
        for (int r2 = 0; r2 < 4; ++r2) {
          int s = (rowb + r2) & (SEQ - 1);
          float c = ct[s * 32 + ii], sn = st[s * 32 + ii];
          float x1 = acc[i][j][r2], x2 = acc[i][j + 2][r2];
          out[(size_t)(rowb + r2) * N + colb + ii]      = f2bf((x1 * c - x2 * sn) * qs);
          out[(size_t)(rowb + r2) * N + colb + ii + 32] = f2bf((x2 * c + x1 * sn) * qs);
        }
      }
    }
  } else {
    // transposed+permuted write: vT[b][c][p(s)], p(s) consecutive over r
    const int bb = m0 >> 11;                   // batch (tile never straddles)
    #pragma unroll
    for (int i = 0; i < 4; ++i) {
      int rowb = m0 + wr * 64 + i * 16 + lg * 4;   // token, ≡0 mod 4
      int s = rowb & (SEQ - 1);
      int pbase = (s & ~31) + (((s & 15) >> 2) << 3) + (((s >> 4) & 1) << 2);
      #pragma unroll
      for (int j = 0; j < 4; ++j) {
        int c = n0 + wc * 64 + j * 16 + l15;
        u16x4 ov = { f2bf(acc[i][j][0]), f2bf(acc[i][j][1]),
                     f2bf(acc[i][j][2]), f2bf(acc[i][j][3]) };
        *(u16x4*)&out[(size_t)bb * SEQ * DIM + (size_t)c * SEQ + pbase] = ov;
      }
    }
  }
}

// ---------------- flash attention v13 ----------------
// QBLK=256: 256 blocks (XCD-swizzled), 512 thr / 8 waves; wave = 32 q-rows
// (unchanged per-wave shape); KVB=64; 3-buf counted-vmcnt pipeline.
// LDS 72KB -> 2 blocks/CU = 16 waves/CU (4/SIMD, 2x R16's TLP); each K/V
// tile now serves 8 waves (FETCH and DMA-write halve again). Staging:
// 24 chunks / 8 waves = 3 loads/thread/stage -> vmcnt(3).
#define KVB 64
__global__ __launch_bounds__(512, 4)
void attn_kernel(const u16* __restrict__ Q, const u16* __restrict__ Kb,
                 const u16* __restrict__ VT, u16* __restrict__ O) {
  __shared__ __align__(16) u16 Ks[3][KVB * 64];        // 8KB/buf
  __shared__ __align__(16) u16 Vs[3][HEAD_DIM * KVB];  // 16KB/buf

  const int tid = threadIdx.x, lane = tid & 63, wid = tid >> 6;   // wid 0..7
  int fl = blockIdx.x + 8 * (blockIdx.y + 16 * blockIdx.z);       // 256 blocks
  fl = (fl & 7) * 32 + (fl >> 3);                                 // XCD swizzle
  const int q0 = (fl & 7) * 256;
  const int h = (fl >> 3) & 15;
  const int b = fl >> 7;
  const int l15 = lane & 15, lg = lane >> 4;

  const u16* kbp = Kb + (size_t)(b * SEQ) * (HEADS * HALF) + h * HALF;
  const u16* vtb = VT + (size_t)b * SEQ * DIM + (size_t)(h * HEAD_DIM) * SEQ;

  // Q fragments (B-operand; col=l15, k=lg*8+j); wave owns rows q0+wid*32..+31
  bf16x8 qf[2][2];
  #pragma unroll
  for (int m = 0; m < 2; ++m)
    #pragma unroll
    for (int ks = 0; ks < 2; ++ks)
      qf[m][ks] = *(const bf16x8*)&Q[(size_t)(b * SEQ + q0 + wid * 32 + m * 16 + l15) * (HEADS * HALF)
                                     + h * HALF + ks * 32 + lg * 8];

  f32x4 o[2][8] = {};
  float l_part[2] = {0.f, 0.f};

  // staging geometry (both tiles: 128B rows, 8-row chunks, XOR-swizzled source)
  const int row8 = lane >> 3;
  const int colB = ((lane & 7) ^ row8) * 16;

  auto stage = [&](u16* KsD, u16* VsD, int kv0) {
    {                                        // K: 8 chunks of 8 kv-rows; wave w -> chunk w
      const u16* src = kbp + (size_t)(kv0 + wid * 8 + row8) * (HEADS * HALF) + (colB >> 1);
      async_copy16(src, KsD + wid * 512);
    }
    #pragma unroll
    for (int i = 0; i < 2; ++i) {            // V: 16 chunks of 8 d-rows; wave w -> {2w, 2w+1}
      int c = wid * 2 + i;
      const u16* src = vtb + (size_t)(c * 8 + row8) * SEQ + kv0 + (colB >> 1);
      async_copy16(src, VsD + c * 512);
    }
  };

  auto compute = [&](const u16* KsP, const u16* VsP) {
    const char* KsB = (const char*)KsP;
    const char* VsB = (const char*)VsP;
    const int kswz = (l15 & 7) << 4;
    // K fragments: kv = nf*16+l15 (4 nf groups), k = ks*32
    bf16x8 kf[2][4];
    #pragma unroll
    for (int ks = 0; ks < 2; ++ks)
      #pragma unroll
      for (int nf = 0; nf < 4; ++nf)
        kf[ks][nf] = *(const bf16x8*)(KsB + (nf * 16 + l15) * 128 + ((ks * 64 + lg * 16) ^ kswz));
    // swapped QK^T: S^T[kv][q]
    f32x4 s[2][4] = {};
    __builtin_amdgcn_s_setprio(1);
    #pragma unroll
    for (int ks = 0; ks < 2; ++ks)
      #pragma unroll
      for (int nf = 0; nf < 4; ++nf) {
        s[0][nf] = mfma16(kf[ks][nf], qf[0][ks], s[0][nf]);
        s[1][nf] = mfma16(kf[ks][nf], qf[1][ks], s[1][nf]);
      }
    __builtin_amdgcn_s_setprio(0);
    // PV in two 32-kv halves (register-P; V rows permuted per 32-block)
    #pragma unroll
    for (int ks2 = 0; ks2 < 2; ++ks2) {
      bf16x8 vf[8];
      #pragma unroll
      for (int db = 0; db < 8; ++db) {
        int row = db * 16 + l15;
        vf[db] = *(const bf16x8*)(VsB + row * 128 + ((ks2 * 64 + lg * 16) ^ ((row & 7) << 4)));
      }
      bf16x8 pa[2];
      #pragma unroll
      for (int m = 0; m < 2; ++m) {
        float p[8];
        #pragma unroll
        for (int nf2 = 0; nf2 < 2; ++nf2)
          #pragma unroll
          for (int r = 0; r < 4; ++r) {
            float v = EXP2F(s[m][ks2 * 2 + nf2][r]);
            p[nf2 * 4 + r] = v;
            l_part[m] += v;
          }
        union { uint32_t u[4]; bf16x8 v8; } pk;
        asm("v_cvt_pk_bf16_f32 %0, %1, %2" : "=v"(pk.u[0]) : "v"(p[0]), "v"(p[1]));
        asm("v_cvt_pk_bf16_f32 %0, %1, %2" : "=v"(pk.u[1]) : "v"(p[2]), "v"(p[3]));
        asm("v_cvt_pk_bf16_f32 %0, %1, %2" : "=v"(pk.u[2]) : "v"(p[4]), "v"(p[5]));
        asm("v_cvt_pk_bf16_f32 %0, %1, %2" : "=v"(pk.u[3]) : "v"(p[6]), "v"(p[7]));
        pa[m] = pk.v8;
      }
      __builtin_amdgcn_s_setprio(1);
      #pragma unroll
      for (int db = 0; db < 8; ++db) {
        o[0][db] = mfma16(pa[0], vf[db], o[0][db]);
        o[1][db] = mfma16(pa[1], vf[db], o[1][db]);
      }
      __builtin_amdgcn_s_setprio(0);
    }
  };

#define WAIT3 asm volatile("s_waitcnt vmcnt(3)" ::: "memory")
#define WAIT0 asm volatile("s_waitcnt vmcnt(0)" ::: "memory")
#define BAR   __builtin_amdgcn_s_barrier()

  // prologue (3 loads/thread per stage; 2 stages in flight -> wait older 3)
  stage(Ks[0], Vs[0], 0);
  stage(Ks[1], Vs[1], KVB);
  WAIT3; BAR;
  // main: NT=32; t = 0..29 in 10 triples (static buffers, counted waits)
  int t = 0;
  for (int i = 0; i < 10; ++i) {
    stage(Ks[2], Vs[2], (t + 2) * KVB); compute(Ks[0], Vs[0]); WAIT3; BAR;
    stage(Ks[0], Vs[0], (t + 3) * KVB); compute(Ks[1], Vs[1]); WAIT3; BAR;
    stage(Ks[1], Vs[1], (t + 4) * KVB); compute(Ks[2], Vs[2]); WAIT3; BAR;
    t += 3;
  }
  // tail: t = 30, 31
  compute(Ks[0], Vs[0]); WAIT0; BAR;
  compute(Ks[1], Vs[1]);

#undef WAIT3
#undef WAIT0
#undef BAR

  // deferred row-sum: lane holds partial for q=m*16+l15 over kv=lg-chunk
  #pragma unroll
  for (int m = 0; m < 2; ++m) {
    float l = l_part[m];
    l += __shfl_xor(l, 16);
    l += __shfl_xor(l, 32);
    float inv[4];
    #pragma unroll
    for (int r = 0; r < 4; ++r)
      inv[r] = 1.0f / __shfl(l, lg * 4 + r);
    #pragma unroll
    for (int db = 0; db < 8; ++db)
      #pragma unroll
      for (int r = 0; r < 4; ++r) {
        int row = q0 + wid * 32 + m * 16 + lg * 4 + r;
        O[(size_t)(b * SEQ + row) * DIM + h * HEAD_DIM + db * 16 + l15] = f2bf(o[m][db][r] * inv[r]);
      }
  }
}

// ---------------- host ----------------
extern "C" void kernel_launch(void* const* d_in, const int* in_sizes, int n_in,
                              void* d_out, int out_size, void* d_ws, size_t ws_size,
                              hipStream_t stream) {
  const float* x     = (const float*)d_in[0];
  const float* wq_d  = (const float*)d_in[1];
  const float* wkv_d = (const float*)d_in[2];
  const float* wq_u  = (const float*)d_in[3];
  const float* wk_u  = (const float*)d_in[4];
  const float* wv_u  = (const float*)d_in[5];
  const float* wo    = (const float*)d_in[6];

  char* ws = (char*)d_ws;
  size_t off = 0;
  auto alloc = [&](size_t bytes) -> void* {
    void* p = ws + off;
    off += (bytes + 255) & ~(size_t)255;
    return p;
  };
  u16* wdT    = (u16*)alloc((size_t)512 * DIM * 2);
  u16* wquT   = (u16*)alloc((size_t)1024 * LATENT * 2);
  u16* wkuT   = (u16*)alloc((size_t)1024 * LATENT * 2);
  u16* wvuT   = (u16*)alloc((size_t)DIM * LATENT * 2);
  u16* woT    = (u16*)alloc((size_t)DIM * DIM * 2);
  u16* lat    = (u16*)alloc((size_t)TOK * 512 * 2);
  u16* latP   = (u16*)alloc((size_t)4 * TOK * 512 * 2);   // split-K4 bf16 partials
  u16* qb     = (u16*)alloc((size_t)TOK * 1024 * 2);
  u16* kb     = (u16*)alloc((size_t)TOK * 1024 * 2);
  u16* vT     = (u16*)alloc((size_t)TOK * DIM * 2);
  u16* ao     = (u16*)alloc((size_t)TOK * DIM * 2);
  float* ct   = (float*)alloc((size_t)SEQ * 32 * 4);
  float* st   = (float*)alloc((size_t)SEQ * 32 * 4);
  (void)in_sizes; (void)n_in; (void)out_size; (void)ws_size;

  // fused prep: all weight transposes + rope tables in one launch
  prep_k<<<dim3(6400), dim3(32, 8), 0, stream>>>(wq_d, wkv_d, wq_u, wk_u, wv_u, wo,
                                                 wdT, wquT, wkuT, wvuT, woT, ct, st);

  // lat partials = x @ [wq_d|wkv_d]: fp32 A reg-staged, split-K4, bf16 partials
  gemm_lat<<<dim3(4, 32, 4), 256, 0, stream>>>(x, DIM, wdT, DIM, latP, TOK, 512, 512);
  // reduce once to bf16 lat (fp32 accumulate of 4 bf16 slabs)
  combine_bf<<<(TOK * 512 / 8 + 255) / 256, 256, 0, stream>>>(latP, lat, TOK * 512 / 8, (size_t)TOK * 512);

  // merged q/k/v up-proj (3-buf counted-vmcnt pipeline)
  upproj_k<<<dim3(1024), 256, 0, stream>>>(lat, wquT, wkuT, wvuT, qb, kb, vT, ct, st);

  // attention: QBLK=256, KVB=64, 8 waves/block, 256 blocks (4 waves/SIMD)
  attn_kernel<<<dim3(SEQ / 256, HEADS, BATCH), 512, 0, stream>>>(qb, kb, vT, ao);

  // out = attn_out @ wo — 3-buf counted-vmcnt pipelined GEMM, fp32 direct
  gemm_wo<<<dim3(16, 32), 256, 0, stream>>>(ao, woT, (float*)d_out);
}

// Round 21
// 154.765 us; speedup vs baseline: 3.5623x; 3.5623x over previous
//
#include <hip/hip_runtime.h>
#include <stdint.h>

typedef unsigned short u16;
typedef __attribute__((ext_vector_type(8))) short bf16x8;
typedef __attribute__((ext_vector_type(8))) unsigned short u16x8;
typedef __attribute__((ext_vector_type(4))) float f32x4;
typedef __attribute__((ext_vector_type(4))) unsigned short u16x4;

#define DIM 2048
#define HEADS 16
#define HEAD_DIM 128
#define HALF 64
#define LATENT 256
#define BATCH 2
#define SEQ 2048
#define TOK (BATCH*SEQ)

#if defined(__has_builtin)
#if __has_builtin(__builtin_amdgcn_exp2f)
#define EXP2F(x) __builtin_amdgcn_exp2f(x)
#endif
#endif
#ifndef EXP2F
#define EXP2F(x) exp2f(x)
#endif

#define SCALE_C 0.18033688011112042f   // (1/sqrt(64)) * log2(e), folded into Q

__device__ __forceinline__ u16 f2bf(float f) {
  uint32_t u = __float_as_uint(f);
  u += 0x7fff + ((u >> 16) & 1);   // round-to-nearest-even
  return (u16)(u >> 16);
}

__device__ __forceinline__ float bf2f(u16 h) {
  return __uint_as_float((uint32_t)h << 16);
}

__device__ __forceinline__ f32x4 mfma16(bf16x8 a, bf16x8 b, f32x4 c) {
  return __builtin_amdgcn_mfma_f32_16x16x32_bf16(a, b, c, 0, 0, 0);
}

__device__ __forceinline__ void async_copy16(const void* g, void* l) {
  __builtin_amdgcn_global_load_lds(
      (const __attribute__((address_space(1))) void*)g,
      (__attribute__((address_space(3))) void*)l, 16, 0, 0);
}

// ---------------- fused prep: 4 weight transposes + rope tables ----------------
__global__ void prep_k(const float* __restrict__ wq_d, const float* __restrict__ wkv_d,
                       const float* __restrict__ wq_u, const float* __restrict__ wk_u,
                       const float* __restrict__ wv_u, const float* __restrict__ wo,
                       u16* __restrict__ wdT, u16* __restrict__ wquT, u16* __restrict__ wkuT,
                       u16* __restrict__ wvuT, u16* __restrict__ woT,
                       float* __restrict__ ct, float* __restrict__ st) {
  __shared__ float tile[32][33];
  const int f = blockIdx.x;
  const int tx = threadIdx.x, ty = threadIdx.y;

  const float* in = nullptr;
  u16* out = nullptr;
  int N = 0, row_off = 0, out_ld = 0, bx = 0, by = 0;

  if (f < 1024) {
    int z = f >> 9, r = f & 511;
    bx = r & 7; by = r >> 3;
    in = z ? wkv_d : wq_d; out = wdT; row_off = z * 256; N = 256; out_ld = 2048;
  } else if (f < 1536) {
    int r = f - 1024; int z = r >> 8; r &= 255;
    bx = r & 31; by = r >> 5;
    in = z ? wk_u : wq_u; out = z ? wkuT : wquT; row_off = 0; N = 1024; out_ld = 256;
  } else if (f < 2048) {
    int r = f - 1536;
    bx = r & 63; by = r >> 6;
    in = wv_u; out = wvuT; row_off = 0; N = 2048; out_ld = 256;
  } else if (f < 6144) {
    int r = f - 2048;
    bx = r & 63; by = r >> 6;
    in = wo; out = woT; row_off = 0; N = 2048; out_ld = 2048;
  } else {
    int t = (f - 6144) * 256 + ty * 32 + tx;
    int i = t & 31, s = t >> 5;
    float invf = expf(-(float)i * 0.28782313662425575f);
    float a = (float)s * invf;
    ct[t] = cosf(a);
    st[t] = sinf(a);
    return;
  }
  int k0 = by * 32, n0 = bx * 32;
  #pragma unroll
  for (int j = 0; j < 32; j += 8)
    tile[ty + j][tx] = in[(size_t)(k0 + ty + j) * N + n0 + tx];
  __syncthreads();
  #pragma unroll
  for (int j = 0; j < 32; j += 8)
    out[(size_t)(n0 + ty + j + row_off) * out_ld + k0 + tx] = f2bf(tile[tx][ty + j]);
}

// ---------------- combine 4 bf16 split-K slabs (fp32 accumulate) ----------------
__global__ void combine_bf(const u16* __restrict__ p, u16* __restrict__ out,
                           int n8, size_t slab) {
  int t = blockIdx.x * 256 + threadIdx.x;
  if (t >= n8) return;
  size_t base = (size_t)t * 8;
  float a[8] = {};
  #pragma unroll
  for (int s = 0; s < 4; ++s) {
    u16x8 v = *(const u16x8*)&p[base + s * slab];
    #pragma unroll
    for (int e = 0; e < 8; ++e) a[e] += bf2f(v[e]);
  }
  u16x8 o;
  #pragma unroll
  for (int e = 0; e < 8; ++e) o[e] = f2bf(a[e]);
  *(u16x8*)&out[base] = o;
}

// ---------------- lat GEMM: A fp32 reg-staged, split-K4, bf16 partials out ----------------
__global__ __launch_bounds__(256)
void gemm_lat(const float* __restrict__ A, int lda, const u16* __restrict__ BT, int ldb,
              u16* __restrict__ Cv, int M, int N, int K) {
  __shared__ __align__(16) u16 As[128 * 32];
  __shared__ __align__(16) u16 Bs[128 * 32];
  const int tid = threadIdx.x;
  const int lane = tid & 63;
  const int wid = tid >> 6;
  const int z = blockIdx.z;
  int koff = z * K;
  const int nb = gridDim.x * gridDim.y;
  int f = blockIdx.x + gridDim.x * blockIdx.y;
  f = (f & 7) * (nb >> 3) + (f >> 3);
  const int m0 = (f / gridDim.x) * 128;
  const int n0 = (f % gridDim.x) * 128;
  const int wr = wid >> 1, wc = wid & 1;
  const int l15 = lane & 15, lg = lane >> 4;
  const int rA = lane >> 2;
  const int kqL = (lane & 3) * 8;
  const int kqS = ((((lane & 3) - ((lane >> 3) & 3)) & 3)) * 8;
  const int sWr = (((lane & 3) + ((lane >> 3) & 3)) & 3) * 8;
  const int rsw = (l15 >> 1) & 3;

  f32x4 acc[4][4] = {};
  const int nk = K / 32;
  for (int kt = 0; kt < nk; ++kt) {
    const int k0 = koff + kt * 32;
    #pragma unroll
    for (int c = 0; c < 2; ++c) {
      int ca = wid * 2 + c;
      const float* ga = A + (size_t)(m0 + ca * 16 + rA) * lda + k0 + kqL;
      float4 v0 = *(const float4*)ga;
      float4 v1 = *(const float4*)(ga + 4);
      union { u16 h[8]; bf16x8 v; } pk;
      pk.h[0] = f2bf(v0.x); pk.h[1] = f2bf(v0.y); pk.h[2] = f2bf(v0.z); pk.h[3] = f2bf(v0.w);
      pk.h[4] = f2bf(v1.x); pk.h[5] = f2bf(v1.y); pk.h[6] = f2bf(v1.z); pk.h[7] = f2bf(v1.w);
      *(bf16x8*)&As[ca * 512 + rA * 32 + sWr] = pk.v;
      const u16* gb = BT + (size_t)(n0 + ca * 16 + rA) * ldb + k0 + kqS;
      async_copy16(gb, &Bs[ca * 512]);
    }
    __syncthreads();
    bf16x8 af[4], bfr[4];
    const int slot = ((lg + rsw) & 3) * 8;
    #pragma unroll
    for (int i = 0; i < 4; ++i) {
      af[i]  = *(const bf16x8*)&As[(wr * 64 + i * 16 + l15) * 32 + slot];
      bfr[i] = *(const bf16x8*)&Bs[(wc * 64 + i * 16 + l15) * 32 + slot];
    }
    #pragma unroll
    for (int i = 0; i < 4; ++i)
      #pragma unroll
      for (int j = 0; j < 4; ++j)
        acc[i][j] = mfma16(af[i], bfr[j], acc[i][j]);
    __syncthreads();
  }
  #pragma unroll
  for (int i = 0; i < 4; ++i) {
    #pragma unroll
    for (int j = 0; j < 4; ++j) {
      int row = m0 + wr * 64 + i * 16 + lg * 4;
      int col = n0 + wc * 64 + j * 16 + l15;
      #pragma unroll
      for (int r = 0; r < 4; ++r)
        Cv[(size_t)z * M * N + (size_t)(row + r) * N + col] = f2bf(acc[i][j][r]);
    }
  }
}

// ---------------- wo GEMM: 3-buf counted-vmcnt pipeline ----------------
__global__ __launch_bounds__(256)
void gemm_wo(const u16* __restrict__ A, const u16* __restrict__ BT,
             float* __restrict__ C) {
  __shared__ __align__(16) u16 As[3][128 * 32];
  __shared__ __align__(16) u16 Bs[3][128 * 32];
  const int tid = threadIdx.x, lane = tid & 63, wid = tid >> 6;
  const int nb = gridDim.x * gridDim.y;          // 512
  int f = blockIdx.x + gridDim.x * blockIdx.y;
  f = (f & 7) * (nb >> 3) + (f >> 3);            // XCD swizzle
  const int m0 = (f / gridDim.x) * 128;
  const int n0 = (f % gridDim.x) * 128;
  const int wr = wid >> 1, wc = wid & 1;
  const int l15 = lane & 15, lg = lane >> 4;
  const int rA = lane >> 2;
  const int kqS = ((((lane & 3) - ((lane >> 3) & 3)) & 3)) * 8;
  const int rsw = (l15 >> 1) & 3;

  f32x4 acc[4][4] = {};

  auto stage = [&](u16* AsD, u16* BsD, int k0) {
    #pragma unroll
    for (int c = 0; c < 2; ++c) {
      int ca = wid * 2 + c;
      async_copy16(A + (size_t)(m0 + ca * 16 + rA) * DIM + k0 + kqS, AsD + ca * 512);
      async_copy16(BT + (size_t)(n0 + ca * 16 + rA) * DIM + k0 + kqS, BsD + ca * 512);
    }
  };
  auto compute = [&](const u16* AsP, const u16* BsP) {
    bf16x8 af[4], bfr[4];
    const int slot = ((lg + rsw) & 3) * 8;
    #pragma unroll
    for (int i = 0; i < 4; ++i) {
      af[i]  = *(const bf16x8*)&AsP[(wr * 64 + i * 16 + l15) * 32 + slot];
      bfr[i] = *(const bf16x8*)&BsP[(wc * 64 + i * 16 + l15) * 32 + slot];
    }
    __builtin_amdgcn_s_setprio(1);
    #pragma unroll
    for (int i = 0; i < 4; ++i)
      #pragma unroll
      for (int j = 0; j < 4; ++j)
        acc[i][j] = mfma16(af[i], bfr[j], acc[i][j]);
    __builtin_amdgcn_s_setprio(0);
  };

#define WAIT4 asm volatile("s_waitcnt vmcnt(4)" ::: "memory")
#define WAIT0 asm volatile("s_waitcnt vmcnt(0)" ::: "memory")
#define BAR   __builtin_amdgcn_s_barrier()

  stage(As[0], Bs[0], 0);
  stage(As[1], Bs[1], 32);
  WAIT4; BAR;
  int t = 0;
  for (int i = 0; i < 20; ++i) {                 // t = 0..59
    stage(As[2], Bs[2], (t + 2) * 32); compute(As[0], Bs[0]); WAIT4; BAR;
    stage(As[0], Bs[0], (t + 3) * 32); compute(As[1], Bs[1]); WAIT4; BAR;
    stage(As[1], Bs[1], (t + 4) * 32); compute(As[2], Bs[2]); WAIT4; BAR;
    t += 3;
  }
  stage(As[2], Bs[2], 62 * 32); compute(As[0], Bs[0]); WAIT4; BAR;
  stage(As[0], Bs[0], 63 * 32); compute(As[1], Bs[1]); WAIT4; BAR;
  compute(As[2], Bs[2]); WAIT0; BAR;
  compute(As[0], Bs[0]);

#undef WAIT4
#undef WAIT0
#undef BAR

  #pragma unroll
  for (int i = 0; i < 4; ++i) {
    #pragma unroll
    for (int j = 0; j < 4; ++j) {
      int row = m0 + wr * 64 + i * 16 + lg * 4;
      int col = n0 + wc * 64 + j * 16 + l15;
      #pragma unroll
      for (int r = 0; r < 4; ++r)
        C[(size_t)(row + r) * DIM + col] = acc[i][j][r];
    }
  }
}

// ---------------- merged up-proj, 3-buf counted-vmcnt pipeline (NT=8) ----------------
__global__ __launch_bounds__(256)
void upproj_k(const u16* __restrict__ A,
              const u16* __restrict__ wquT, const u16* __restrict__ wkuT,
              const u16* __restrict__ wvuT,
              u16* __restrict__ qb, u16* __restrict__ kb, u16* __restrict__ vT,
              const float* __restrict__ ct, const float* __restrict__ st) {
  __shared__ __align__(16) u16 As[3][128 * 32];
  __shared__ __align__(16) u16 Bs[3][128 * 32];
  const int tid = threadIdx.x;
  const int lane = tid & 63;
  const int wid = tid >> 6;
  int f = blockIdx.x;
  f = (f & 7) * 128 + (f >> 3);          // XCD swizzle over flat 1024
  const u16* BT; u16* out; int N, a_off, seg, r;
  if (f < 256)      { seg = 0; r = f;       BT = wquT; out = qb; N = 1024; a_off = 0; }
  else if (f < 512) { seg = 1; r = f - 256; BT = wkuT; out = kb; N = 1024; a_off = 256; }
  else              { seg = 2; r = f - 512; BT = wvuT; out = vT; N = 2048; a_off = 256; }
  const int gx = (seg == 2) ? 16 : 8;
  const int m0 = (r / gx) * 128;
  const int n0 = (r % gx) * 128;
  const int wr = wid >> 1, wc = wid & 1;
  const int l15 = lane & 15, lg = lane >> 4;
  const int rA = lane >> 2;
  const int kqS = ((((lane & 3) - ((lane >> 3) & 3)) & 3)) * 8;
  const int rsw = (l15 >> 1) & 3;

  f32x4 acc[4][4] = {};

  auto stage = [&](u16* AsD, u16* BsD, int k0) {
    #pragma unroll
    for (int c = 0; c < 2; ++c) {
      int ca = wid * 2 + c;
      async_copy16(A + (size_t)(m0 + ca * 16 + rA) * 512 + a_off + k0 + kqS, AsD + ca * 512);
      async_copy16(BT + (size_t)(n0 + ca * 16 + rA) * LATENT + k0 + kqS, BsD + ca * 512);
    }
  };
  auto compute = [&](const u16* AsP, const u16* BsP) {
    bf16x8 af[4], bfr[4];
    const int slot = ((lg + rsw) & 3) * 8;
    #pragma unroll
    for (int i = 0; i < 4; ++i) {
      af[i]  = *(const bf16x8*)&AsP[(wr * 64 + i * 16 + l15) * 32 + slot];
      bfr[i] = *(const bf16x8*)&BsP[(wc * 64 + i * 16 + l15) * 32 + slot];
    }
    __builtin_amdgcn_s_setprio(1);
    #pragma unroll
    for (int i = 0; i < 4; ++i)
      #pragma unroll
      for (int j = 0; j < 4; ++j)
        acc[i][j] = mfma16(af[i], bfr[j], acc[i][j]);
    __builtin_amdgcn_s_setprio(0);
  };

#define WAIT4 asm volatile("s_waitcnt vmcnt(4)" ::: "memory")
#define WAIT0 asm volatile("s_waitcnt vmcnt(0)" ::: "memory")
#define BAR   __builtin_amdgcn_s_barrier()

  // NT = 8 K-steps (K=256, BK=32)
  stage(As[0], Bs[0], 0);
  stage(As[1], Bs[1], 32);
  WAIT4; BAR;
  stage(As[2], Bs[2],  64); compute(As[0], Bs[0]); WAIT4; BAR;
  stage(As[0], Bs[0],  96); compute(As[1], Bs[1]); WAIT4; BAR;
  stage(As[1], Bs[1], 128); compute(As[2], Bs[2]); WAIT4; BAR;
  stage(As[2], Bs[2], 160); compute(As[0], Bs[0]); WAIT4; BAR;
  stage(As[0], Bs[0], 192); compute(As[1], Bs[1]); WAIT4; BAR;
  stage(As[1], Bs[1], 224); compute(As[2], Bs[2]); WAIT4; BAR;
  compute(As[0], Bs[0]); WAIT0; BAR;
  compute(As[1], Bs[1]);

#undef WAIT4
#undef WAIT0
#undef BAR

  if (seg <= 1) {
    const float qs = seg ? 1.0f : SCALE_C;
    #pragma unroll
    for (int i = 0; i < 4; ++i) {
      int rowb = m0 + wr * 64 + i * 16 + lg * 4;
      #pragma unroll
      for (int j = 0; j < 2; ++j) {
        int ii = j * 16 + l15;                 // 0..31 within head
        int colb = n0 + wc * 64;
        #pragma unroll
        for (int r2 = 0; r2 < 4; ++r2) {
          int s = (rowb + r2) & (SEQ - 1);
          float c = ct[s * 32 + ii], sn = st[s * 32 + ii];
          float x1 = acc[i][j][r2], x2 = acc[i][j + 2][r2];
          out[(size_t)(rowb + r2) * N + colb + ii]      = f2bf((x1 * c - x2 * sn) * qs);
          out[(size_t)(rowb + r2) * N + colb + ii + 32] = f2bf((x2 * c + x1 * sn) * qs);
        }
      }
    }
  } else {
    // transposed+permuted write: vT[b][c][p(s)], p(s) consecutive over r
    const int bb = m0 >> 11;                   // batch (tile never straddles)
    #pragma unroll
    for (int i = 0; i < 4; ++i) {
      int rowb = m0 + wr * 64 + i * 16 + lg * 4;   // token, ≡0 mod 4
      int s = rowb & (SEQ - 1);
      int pbase = (s & ~31) + (((s & 15) >> 2) << 3) + (((s >> 4) & 1) << 2);
      #pragma unroll
      for (int j = 0; j < 4; ++j) {
        int c = n0 + wc * 64 + j * 16 + l15;
        u16x4 ov = { f2bf(acc[i][j][0]), f2bf(acc[i][j][1]),
                     f2bf(acc[i][j][2]), f2bf(acc[i][j][3]) };
        *(u16x4*)&out[(size_t)bb * SEQ * DIM + (size_t)c * SEQ + pbase] = ov;
      }
    }
  }
}

// ---------------- flash attention v13b ----------------
// QBLK=256: 256 blocks (XCD-swizzled), 512 thr / 8 waves; wave = 32 q-rows;
// KVB=64; 3-buf counted-vmcnt pipeline. launch_bounds(512,2): empirically
// hipcc treats the 2nd arg as blocks/CU -> 2 blocks x 8 waves = 16 waves/CU,
// VGPR budget 128 (kernel needs ~116 -> no spill; R20's (512,4) gave 64 and
// spilled catastrophically). Staging: 24 chunks / 8 waves = 3 loads/thread
// -> vmcnt(3).
#define KVB 64
__global__ __launch_bounds__(512, 2)
void attn_kernel(const u16* __restrict__ Q, const u16* __restrict__ Kb,
                 const u16* __restrict__ VT, u16* __restrict__ O) {
  __shared__ __align__(16) u16 Ks[3][KVB * 64];        // 8KB/buf
  __shared__ __align__(16) u16 Vs[3][HEAD_DIM * KVB];  // 16KB/buf

  const int tid = threadIdx.x, lane = tid & 63, wid = tid >> 6;   // wid 0..7
  int fl = blockIdx.x + 8 * (blockIdx.y + 16 * blockIdx.z);       // 256 blocks
  fl = (fl & 7) * 32 + (fl >> 3);                                 // XCD swizzle
  const int q0 = (fl & 7) * 256;
  const int h = (fl >> 3) & 15;
  const int b = fl >> 7;
  const int l15 = lane & 15, lg = lane >> 4;

  const u16* kbp = Kb + (size_t)(b * SEQ) * (HEADS * HALF) + h * HALF;
  const u16* vtb = VT + (size_t)b * SEQ * DIM + (size_t)(h * HEAD_DIM) * SEQ;

  // Q fragments (B-operand; col=l15, k=lg*8+j); wave owns rows q0+wid*32..+31
  bf16x8 qf[2][2];
  #pragma unroll
  for (int m = 0; m < 2; ++m)
    #pragma unroll
    for (int ks = 0; ks < 2; ++ks)
      qf[m][ks] = *(const bf16x8*)&Q[(size_t)(b * SEQ + q0 + wid * 32 + m * 16 + l15) * (HEADS * HALF)
                                     + h * HALF + ks * 32 + lg * 8];

  f32x4 o[2][8] = {};
  float l_part[2] = {0.f, 0.f};

  // staging geometry (both tiles: 128B rows, 8-row chunks, XOR-swizzled source)
  const int row8 = lane >> 3;
  const int colB = ((lane & 7) ^ row8) * 16;

  auto stage = [&](u16* KsD, u16* VsD, int kv0) {
    {                                        // K: 8 chunks of 8 kv-rows; wave w -> chunk w
      const u16* src = kbp + (size_t)(kv0 + wid * 8 + row8) * (HEADS * HALF) + (colB >> 1);
      async_copy16(src, KsD + wid * 512);
    }
    #pragma unroll
    for (int i = 0; i < 2; ++i) {            // V: 16 chunks of 8 d-rows; wave w -> {2w, 2w+1}
      int c = wid * 2 + i;
      const u16* src = vtb + (size_t)(c * 8 + row8) * SEQ + kv0 + (colB >> 1);
      async_copy16(src, VsD + c * 512);
    }
  };

  auto compute = [&](const u16* KsP, const u16* VsP) {
    const char* KsB = (const char*)KsP;
    const char* VsB = (const char*)VsP;
    const int kswz = (l15 & 7) << 4;
    // K fragments: kv = nf*16+l15 (4 nf groups), k = ks*32
    bf16x8 kf[2][4];
    #pragma unroll
    for (int ks = 0; ks < 2; ++ks)
      #pragma unroll
      for (int nf = 0; nf < 4; ++nf)
        kf[ks][nf] = *(const bf16x8*)(KsB + (nf * 16 + l15) * 128 + ((ks * 64 + lg * 16) ^ kswz));
    // swapped QK^T: S^T[kv][q]
    f32x4 s[2][4] = {};
    __builtin_amdgcn_s_setprio(1);
    #pragma unroll
    for (int ks = 0; ks < 2; ++ks)
      #pragma unroll
      for (int nf = 0; nf < 4; ++nf) {
        s[0][nf] = mfma16(kf[ks][nf], qf[0][ks], s[0][nf]);
        s[1][nf] = mfma16(kf[ks][nf], qf[1][ks], s[1][nf]);
      }
    __builtin_amdgcn_s_setprio(0);
    // PV in two 32-kv halves (register-P; V rows permuted per 32-block)
    #pragma unroll
    for (int ks2 = 0; ks2 < 2; ++ks2) {
      bf16x8 vf[8];
      #pragma unroll
      for (int db = 0; db < 8; ++db) {
        int row = db * 16 + l15;
        vf[db] = *(const bf16x8*)(VsB + row * 128 + ((ks2 * 64 + lg * 16) ^ ((row & 7) << 4)));
      }
      bf16x8 pa[2];
      #pragma unroll
      for (int m = 0; m < 2; ++m) {
        float p[8];
        #pragma unroll
        for (int nf2 = 0; nf2 < 2; ++nf2)
          #pragma unroll
          for (int r = 0; r < 4; ++r) {
            float v = EXP2F(s[m][ks2 * 2 + nf2][r]);
            p[nf2 * 4 + r] = v;
            l_part[m] += v;
          }
        union { uint32_t u[4]; bf16x8 v8; } pk;
        asm("v_cvt_pk_bf16_f32 %0, %1, %2" : "=v"(pk.u[0]) : "v"(p[0]), "v"(p[1]));
        asm("v_cvt_pk_bf16_f32 %0, %1, %2" : "=v"(pk.u[1]) : "v"(p[2]), "v"(p[3]));
        asm("v_cvt_pk_bf16_f32 %0, %1, %2" : "=v"(pk.u[2]) : "v"(p[4]), "v"(p[5]));
        asm("v_cvt_pk_bf16_f32 %0, %1, %2" : "=v"(pk.u[3]) : "v"(p[6]), "v"(p[7]));
        pa[m] = pk.v8;
      }
      __builtin_amdgcn_s_setprio(1);
      #pragma unroll
      for (int db = 0; db < 8; ++db) {
        o[0][db] = mfma16(pa[0], vf[db], o[0][db]);
        o[1][db] = mfma16(pa[1], vf[db], o[1][db]);
      }
      __builtin_amdgcn_s_setprio(0);
    }
  };

#define WAIT3 asm volatile("s_waitcnt vmcnt(3)" ::: "memory")
#define WAIT0 asm volatile("s_waitcnt vmcnt(0)" ::: "memory")
#define BAR   __builtin_amdgcn_s_barrier()

  // prologue (3 loads/thread per stage; 2 stages in flight -> wait older 3)
  stage(Ks[0], Vs[0], 0);
  stage(Ks[1], Vs[1], KVB);
  WAIT3; BAR;
  // main: NT=32; t = 0..29 in 10 triples (static buffers, counted waits)
  int t = 0;
  for (int i = 0; i < 10; ++i) {
    stage(Ks[2], Vs[2], (t + 2) * KVB); compute(Ks[0], Vs[0]); WAIT3; BAR;
    stage(Ks[0], Vs[0], (t + 3) * KVB); compute(Ks[1], Vs[1]); WAIT3; BAR;
    stage(Ks[1], Vs[1], (t + 4) * KVB); compute(Ks[2], Vs[2]); WAIT3; BAR;
    t += 3;
  }
  // tail: t = 30, 31
  compute(Ks[0], Vs[0]); WAIT0; BAR;
  compute(Ks[1], Vs[1]);

#undef WAIT3
#undef WAIT0
#undef BAR

  // deferred row-sum: lane holds partial for q=m*16+l15 over kv=lg-chunk
  #pragma unroll
  for (int m = 0; m < 2; ++m) {
    float l = l_part[m];
    l += __shfl_xor(l, 16);
    l += __shfl_xor(l, 32);
    float inv[4];
    #pragma unroll
    for (int r = 0; r < 4; ++r)
      inv[r] = 1.0f / __shfl(l, lg * 4 + r);
    #pragma unroll
    for (int db = 0; db < 8; ++db)
      #pragma unroll
      for (int r = 0; r < 4; ++r) {
        int row = q0 + wid * 32 + m * 16 + lg * 4 + r;
        O[(size_t)(b * SEQ + row) * DIM + h * HEAD_DIM + db * 16 + l15] = f2bf(o[m][db][r] * inv[r]);
      }
  }
}

// ---------------- host ----------------
extern "C" void kernel_launch(void* const* d_in, const int* in_sizes, int n_in,
                              void* d_out, int out_size, void* d_ws, size_t ws_size,
                              hipStream_t stream) {
  const float* x     = (const float*)d_in[0];
  const float* wq_d  = (const float*)d_in[1];
  const float* wkv_d = (const float*)d_in[2];
  const float* wq_u  = (const float*)d_in[3];
  const float* wk_u  = (const float*)d_in[4];
  const float* wv_u  = (const float*)d_in[5];
  const float* wo    = (const float*)d_in[6];

  char* ws = (char*)d_ws;
  size_t off = 0;
  auto alloc = [&](size_t bytes) -> void* {
    void* p = ws + off;
    off += (bytes + 255) & ~(size_t)255;
    return p;
  };
  u16* wdT    = (u16*)alloc((size_t)512 * DIM * 2);
  u16* wquT   = (u16*)alloc((size_t)1024 * LATENT * 2);
  u16* wkuT   = (u16*)alloc((size_t)1024 * LATENT * 2);
  u16* wvuT   = (u16*)alloc((size_t)DIM * LATENT * 2);
  u16* woT    = (u16*)alloc((size_t)DIM * DIM * 2);
  u16* lat    = (u16*)alloc((size_t)TOK * 512 * 2);
  u16* latP   = (u16*)alloc((size_t)4 * TOK * 512 * 2);   // split-K4 bf16 partials
  u16* qb     = (u16*)alloc((size_t)TOK * 1024 * 2);
  u16* kb     = (u16*)alloc((size_t)TOK * 1024 * 2);
  u16* vT     = (u16*)alloc((size_t)TOK * DIM * 2);
  u16* ao     = (u16*)alloc((size_t)TOK * DIM * 2);
  float* ct   = (float*)alloc((size_t)SEQ * 32 * 4);
  float* st   = (float*)alloc((size_t)SEQ * 32 * 4);
  (void)in_sizes; (void)n_in; (void)out_size; (void)ws_size;

  // fused prep: all weight transposes + rope tables in one launch
  prep_k<<<dim3(6400), dim3(32, 8), 0, stream>>>(wq_d, wkv_d, wq_u, wk_u, wv_u, wo,
                                                 wdT, wquT, wkuT, wvuT, woT, ct, st);

  // lat partials = x @ [wq_d|wkv_d]: fp32 A reg-staged, split-K4, bf16 partials
  gemm_lat<<<dim3(4, 32, 4), 256, 0, stream>>>(x, DIM, wdT, DIM, latP, TOK, 512, 512);
  // reduce once to bf16 lat (fp32 accumulate of 4 bf16 slabs)
  combine_bf<<<(TOK * 512 / 8 + 255) / 256, 256, 0, stream>>>(latP, lat, TOK * 512 / 8, (size_t)TOK * 512);

  // merged q/k/v up-proj (3-buf counted-vmcnt pipeline)
  upproj_k<<<dim3(1024), 256, 0, stream>>>(lat, wquT, wkuT, wvuT, qb, kb, vT, ct, st);

  // attention: QBLK=256, KVB=64, 8 waves/block, 256 blocks (2 blocks/CU)
  attn_kernel<<<dim3(SEQ / 256, HEADS, BATCH), 512, 0, stream>>>(qb, kb, vT, ao);

  // out = attn_out @ wo — 3-buf counted-vmcnt pipelined GEMM, fp32 direct
  gemm_wo<<<dim3(16, 32), 256, 0, stream>>>(ao, woT, (float*)d_out);
}

// Round 23
// 153.980 us; speedup vs baseline: 3.5805x; 1.0051x over previous
//
#include <hip/hip_runtime.h>
#include <stdint.h>

typedef unsigned short u16;
typedef __attribute__((ext_vector_type(8))) short bf16x8;
typedef __attribute__((ext_vector_type(8))) unsigned short u16x8;
typedef __attribute__((ext_vector_type(4))) float f32x4;
typedef __attribute__((ext_vector_type(4))) unsigned short u16x4;

#define DIM 2048
#define HEADS 16
#define HEAD_DIM 128
#define HALF 64
#define LATENT 256
#define BATCH 2
#define SEQ 2048
#define TOK (BATCH*SEQ)

#if defined(__has_builtin)
#if __has_builtin(__builtin_amdgcn_exp2f)
#define EXP2F(x) __builtin_amdgcn_exp2f(x)
#endif
#endif
#ifndef EXP2F
#define EXP2F(x) exp2f(x)
#endif

#define SCALE_C 0.18033688011112042f   // (1/sqrt(64)) * log2(e), folded into Q

__device__ __forceinline__ u16 f2bf(float f) {
  uint32_t u = __float_as_uint(f);
  u += 0x7fff + ((u >> 16) & 1);   // round-to-nearest-even
  return (u16)(u >> 16);
}

__device__ __forceinline__ float bf2f(u16 h) {
  return __uint_as_float((uint32_t)h << 16);
}

__device__ __forceinline__ f32x4 mfma16(bf16x8 a, bf16x8 b, f32x4 c) {
  return __builtin_amdgcn_mfma_f32_16x16x32_bf16(a, b, c, 0, 0, 0);
}

__device__ __forceinline__ void async_copy16(const void* g, void* l) {
  __builtin_amdgcn_global_load_lds(
      (const __attribute__((address_space(1))) void*)g,
      (__attribute__((address_space(3))) void*)l, 16, 0, 0);
}

// ---------------- fused prep: 4 weight transposes + rope tables ----------------
__global__ void prep_k(const float* __restrict__ wq_d, const float* __restrict__ wkv_d,
                       const float* __restrict__ wq_u, const float* __restrict__ wk_u,
                       const float* __restrict__ wv_u, const float* __restrict__ wo,
                       u16* __restrict__ wdT, u16* __restrict__ wquT, u16* __restrict__ wkuT,
                       u16* __restrict__ wvuT, u16* __restrict__ woT,
                       float* __restrict__ ct, float* __restrict__ st) {
  __shared__ float tile[32][33];
  const int f = blockIdx.x;
  const int tx = threadIdx.x, ty = threadIdx.y;

  const float* in = nullptr;
  u16* out = nullptr;
  int N = 0, row_off = 0, out_ld = 0, bx = 0, by = 0;

  if (f < 1024) {
    int z = f >> 9, r = f & 511;
    bx = r & 7; by = r >> 3;
    in = z ? wkv_d : wq_d; out = wdT; row_off = z * 256; N = 256; out_ld = 2048;
  } else if (f < 1536) {
    int r = f - 1024; int z = r >> 8; r &= 255;
    bx = r & 31; by = r >> 5;
    in = z ? wk_u : wq_u; out = z ? wkuT : wquT; row_off = 0; N = 1024; out_ld = 256;
  } else if (f < 2048) {
    int r = f - 1536;
    bx = r & 63; by = r >> 6;
    in = wv_u; out = wvuT; row_off = 0; N = 2048; out_ld = 256;
  } else if (f < 6144) {
    int r = f - 2048;
    bx = r & 63; by = r >> 6;
    in = wo; out = woT; row_off = 0; N = 2048; out_ld = 2048;
  } else {
    int t = (f - 6144) * 256 + ty * 32 + tx;
    int i = t & 31, s = t >> 5;
    float invf = expf(-(float)i * 0.28782313662425575f);
    float a = (float)s * invf;
    ct[t] = cosf(a);
    st[t] = sinf(a);
    return;
  }
  int k0 = by * 32, n0 = bx * 32;
  #pragma unroll
  for (int j = 0; j < 32; j += 8)
    tile[ty + j][tx] = in[(size_t)(k0 + ty + j) * N + n0 + tx];
  __syncthreads();
  #pragma unroll
  for (int j = 0; j < 32; j += 8)
    out[(size_t)(n0 + ty + j + row_off) * out_ld + k0 + tx] = f2bf(tile[tx][ty + j]);
}

// ---------------- combine 4 bf16 split-K slabs (fp32 accumulate) ----------------
__global__ void combine_bf(const u16* __restrict__ p, u16* __restrict__ out,
                           int n8, size_t slab) {
  int t = blockIdx.x * 256 + threadIdx.x;
  if (t >= n8) return;
  size_t base = (size_t)t * 8;
  float a[8] = {};
  #pragma unroll
  for (int s = 0; s < 4; ++s) {
    u16x8 v = *(const u16x8*)&p[base + s * slab];
    #pragma unroll
    for (int e = 0; e < 8; ++e) a[e] += bf2f(v[e]);
  }
  u16x8 o;
  #pragma unroll
  for (int e = 0; e < 8; ++e) o[e] = f2bf(a[e]);
  *(u16x8*)&out[base] = o;
}

// ---------------- lat GEMM: A fp32 reg-staged, split-K4, bf16 partials out ----------------
__global__ __launch_bounds__(256)
void gemm_lat(const float* __restrict__ A, int lda, const u16* __restrict__ BT, int ldb,
              u16* __restrict__ Cv, int M, int N, int K) {
  __shared__ __align__(16) u16 As[128 * 32];
  __shared__ __align__(16) u16 Bs[128 * 32];
  const int tid = threadIdx.x;
  const int lane = tid & 63;
  const int wid = tid >> 6;
  const int z = blockIdx.z;
  int koff = z * K;
  const int nb = gridDim.x * gridDim.y;
  int f = blockIdx.x + gridDim.x * blockIdx.y;
  f = (f & 7) * (nb >> 3) + (f >> 3);
  const int m0 = (f / gridDim.x) * 128;
  const int n0 = (f % gridDim.x) * 128;
  const int wr = wid >> 1, wc = wid & 1;
  const int l15 = lane & 15, lg = lane >> 4;
  const int rA = lane >> 2;
  const int kqL = (lane & 3) * 8;
  const int kqS = ((((lane & 3) - ((lane >> 3) & 3)) & 3)) * 8;
  const int sWr = (((lane & 3) + ((lane >> 3) & 3)) & 3) * 8;
  const int rsw = (l15 >> 1) & 3;

  f32x4 acc[4][4] = {};
  const int nk = K / 32;
  for (int kt = 0; kt < nk; ++kt) {
    const int k0 = koff + kt * 32;
    #pragma unroll
    for (int c = 0; c < 2; ++c) {
      int ca = wid * 2 + c;
      const float* ga = A + (size_t)(m0 + ca * 16 + rA) * lda + k0 + kqL;
      float4 v0 = *(const float4*)ga;
      float4 v1 = *(const float4*)(ga + 4);
      union { u16 h[8]; bf16x8 v; } pk;
      pk.h[0] = f2bf(v0.x); pk.h[1] = f2bf(v0.y); pk.h[2] = f2bf(v0.z); pk.h[3] = f2bf(v0.w);
      pk.h[4] = f2bf(v1.x); pk.h[5] = f2bf(v1.y); pk.h[6] = f2bf(v1.z); pk.h[7] = f2bf(v1.w);
      *(bf16x8*)&As[ca * 512 + rA * 32 + sWr] = pk.v;
      const u16* gb = BT + (size_t)(n0 + ca * 16 + rA) * ldb + k0 + kqS;
      async_copy16(gb, &Bs[ca * 512]);
    }
    __syncthreads();
    bf16x8 af[4], bfr[4];
    const int slot = ((lg + rsw) & 3) * 8;
    #pragma unroll
    for (int i = 0; i < 4; ++i) {
      af[i]  = *(const bf16x8*)&As[(wr * 64 + i * 16 + l15) * 32 + slot];
      bfr[i] = *(const bf16x8*)&Bs[(wc * 64 + i * 16 + l15) * 32 + slot];
    }
    #pragma unroll
    for (int i = 0; i < 4; ++i)
      #pragma unroll
      for (int j = 0; j < 4; ++j)
        acc[i][j] = mfma16(af[i], bfr[j], acc[i][j]);
    __syncthreads();
  }
  #pragma unroll
  for (int i = 0; i < 4; ++i) {
    #pragma unroll
    for (int j = 0; j < 4; ++j) {
      int row = m0 + wr * 64 + i * 16 + lg * 4;
      int col = n0 + wc * 64 + j * 16 + l15;
      #pragma unroll
      for (int r = 0; r < 4; ++r)
        Cv[(size_t)z * M * N + (size_t)(row + r) * N + col] = f2bf(acc[i][j][r]);
    }
  }
}

// ---------------- wo GEMM: 3-buf counted-vmcnt pipeline ----------------
__global__ __launch_bounds__(256)
void gemm_wo(const u16* __restrict__ A, const u16* __restrict__ BT,
             float* __restrict__ C) {
  __shared__ __align__(16) u16 As[3][128 * 32];
  __shared__ __align__(16) u16 Bs[3][128 * 32];
  const int tid = threadIdx.x, lane = tid & 63, wid = tid >> 6;
  const int nb = gridDim.x * gridDim.y;          // 512
  int f = blockIdx.x + gridDim.x * blockIdx.y;
  f = (f & 7) * (nb >> 3) + (f >> 3);            // XCD swizzle
  const int m0 = (f / gridDim.x) * 128;
  const int n0 = (f % gridDim.x) * 128;
  const int wr = wid >> 1, wc = wid & 1;
  const int l15 = lane & 15, lg = lane >> 4;
  const int rA = lane >> 2;
  const int kqS = ((((lane & 3) - ((lane >> 3) & 3)) & 3)) * 8;
  const int rsw = (l15 >> 1) & 3;

  f32x4 acc[4][4] = {};

  auto stage = [&](u16* AsD, u16* BsD, int k0) {
    #pragma unroll
    for (int c = 0; c < 2; ++c) {
      int ca = wid * 2 + c;
      async_copy16(A + (size_t)(m0 + ca * 16 + rA) * DIM + k0 + kqS, AsD + ca * 512);
      async_copy16(BT + (size_t)(n0 + ca * 16 + rA) * DIM + k0 + kqS, BsD + ca * 512);
    }
  };
  auto compute = [&](const u16* AsP, const u16* BsP) {
    bf16x8 af[4], bfr[4];
    const int slot = ((lg + rsw) & 3) * 8;
    #pragma unroll
    for (int i = 0; i < 4; ++i) {
      af[i]  = *(const bf16x8*)&AsP[(wr * 64 + i * 16 + l15) * 32 + slot];
      bfr[i] = *(const bf16x8*)&BsP[(wc * 64 + i * 16 + l15) * 32 + slot];
    }
    __builtin_amdgcn_s_setprio(1);
    #pragma unroll
    for (int i = 0; i < 4; ++i)
      #pragma unroll
      for (int j = 0; j < 4; ++j)
        acc[i][j] = mfma16(af[i], bfr[j], acc[i][j]);
    __builtin_amdgcn_s_setprio(0);
  };

#define WAIT4 asm volatile("s_waitcnt vmcnt(4)" ::: "memory")
#define WAIT0 asm volatile("s_waitcnt vmcnt(0)" ::: "memory")
#define BAR   __builtin_amdgcn_s_barrier()

  stage(As[0], Bs[0], 0);
  stage(As[1], Bs[1], 32);
  WAIT4; BAR;
  int t = 0;
  for (int i = 0; i < 20; ++i) {                 // t = 0..59
    stage(As[2], Bs[2], (t + 2) * 32); compute(As[0], Bs[0]); WAIT4; BAR;
    stage(As[0], Bs[0], (t + 3) * 32); compute(As[1], Bs[1]); WAIT4; BAR;
    stage(As[1], Bs[1], (t + 4) * 32); compute(As[2], Bs[2]); WAIT4; BAR;
    t += 3;
  }
  stage(As[2], Bs[2], 62 * 32); compute(As[0], Bs[0]); WAIT4; BAR;
  stage(As[0], Bs[0], 63 * 32); compute(As[1], Bs[1]); WAIT4; BAR;
  compute(As[2], Bs[2]); WAIT0; BAR;
  compute(As[0], Bs[0]);

#undef WAIT4
#undef WAIT0
#undef BAR

  #pragma unroll
  for (int i = 0; i < 4; ++i) {
    #pragma unroll
    for (int j = 0; j < 4; ++j) {
      int row = m0 + wr * 64 + i * 16 + lg * 4;
      int col = n0 + wc * 64 + j * 16 + l15;
      #pragma unroll
      for (int r = 0; r < 4; ++r)
        C[(size_t)(row + r) * DIM + col] = acc[i][j][r];
    }
  }
}

// ---------------- merged up-proj, 3-buf counted-vmcnt pipeline (NT=8) ----------------
__global__ __launch_bounds__(256)
void upproj_k(const u16* __restrict__ A,
              const u16* __restrict__ wquT, const u16* __restrict__ wkuT,
              const u16* __restrict__ wvuT,
              u16* __restrict__ qb, u16* __restrict__ kb, u16* __restrict__ vT,
              const float* __restrict__ ct, const float* __restrict__ st) {
  __shared__ __align__(16) u16 As[3][128 * 32];
  __shared__ __align__(16) u16 Bs[3][128 * 32];
  const int tid = threadIdx.x;
  const int lane = tid & 63;
  const int wid = tid >> 6;
  int f = blockIdx.x;
  f = (f & 7) * 128 + (f >> 3);          // XCD swizzle over flat 1024
  const u16* BT; u16* out; int N, a_off, seg, r;
  if (f < 256)      { seg = 0; r = f;       BT = wquT; out = qb; N = 1024; a_off = 0; }
  else if (f < 512) { seg = 1; r = f - 256; BT = wkuT; out = kb; N = 1024; a_off = 256; }
  else              { seg = 2; r = f - 512; BT = wvuT; out = vT; N = 2048; a_off = 256; }
  const int gx = (seg == 2) ? 16 : 8;
  const int m0 = (r / gx) * 128;
  const int n0 = (r % gx) * 128;
  const int wr = wid >> 1, wc = wid & 1;
  const int l15 = lane & 15, lg = lane >> 4;
  const int rA = lane >> 2;
  const int kqS = ((((lane & 3) - ((lane >> 3) & 3)) & 3)) * 8;
  const int rsw = (l15 >> 1) & 3;

  f32x4 acc[4][4] = {};

  auto stage = [&](u16* AsD, u16* BsD, int k0) {
    #pragma unroll
    for (int c = 0; c < 2; ++c) {
      int ca = wid * 2 + c;
      async_copy16(A + (size_t)(m0 + ca * 16 + rA) * 512 + a_off + k0 + kqS, AsD + ca * 512);
      async_copy16(BT + (size_t)(n0 + ca * 16 + rA) * LATENT + k0 + kqS, BsD + ca * 512);
    }
  };
  auto compute = [&](const u16* AsP, const u16* BsP) {
    bf16x8 af[4], bfr[4];
    const int slot = ((lg + rsw) & 3) * 8;
    #pragma unroll
    for (int i = 0; i < 4; ++i) {
      af[i]  = *(const bf16x8*)&AsP[(wr * 64 + i * 16 + l15) * 32 + slot];
      bfr[i] = *(const bf16x8*)&BsP[(wc * 64 + i * 16 + l15) * 32 + slot];
    }
    __builtin_amdgcn_s_setprio(1);
    #pragma unroll
    for (int i = 0; i < 4; ++i)
      #pragma unroll
      for (int j = 0; j < 4; ++j)
        acc[i][j] = mfma16(af[i], bfr[j], acc[i][j]);
    __builtin_amdgcn_s_setprio(0);
  };

#define WAIT4 asm volatile("s_waitcnt vmcnt(4)" ::: "memory")
#define WAIT0 asm volatile("s_waitcnt vmcnt(0)" ::: "memory")
#define BAR   __builtin_amdgcn_s_barrier()

  // NT = 8 K-steps (K=256, BK=32)
  stage(As[0], Bs[0], 0);
  stage(As[1], Bs[1], 32);
  WAIT4; BAR;
  stage(As[2], Bs[2],  64); compute(As[0], Bs[0]); WAIT4; BAR;
  stage(As[0], Bs[0],  96); compute(As[1], Bs[1]); WAIT4; BAR;
  stage(As[1], Bs[1], 128); compute(As[2], Bs[2]); WAIT4; BAR;
  stage(As[2], Bs[2], 160); compute(As[0], Bs[0]); WAIT4; BAR;
  stage(As[0], Bs[0], 192); compute(As[1], Bs[1]); WAIT4; BAR;
  stage(As[1], Bs[1], 224); compute(As[2], Bs[2]); WAIT4; BAR;
  compute(As[0], Bs[0]); WAIT0; BAR;
  compute(As[1], Bs[1]);

#undef WAIT4
#undef WAIT0
#undef BAR

  if (seg <= 1) {
    const float qs = seg ? 1.0f : SCALE_C;
    #pragma unroll
    for (int i = 0; i < 4; ++i) {
      int rowb = m0 + wr * 64 + i * 16 + lg * 4;
      #pragma unroll
      for (int j = 0; j < 2; ++j) {
        int ii = j * 16 + l15;                 // 0..31 within head
        int colb = n0 + wc * 64;
        #pragma unroll
        for (int r2 = 0; r2 < 4; ++r2) {
          int s = (rowb + r2) & (SEQ - 1);
          float c = ct[s * 32 + ii], sn = st[s * 32 + ii];
          float x1 = acc[i][j][r2], x2 = acc[i][j + 2][r2];
          out[(size_t)(rowb + r2) * N + colb + ii]      = f2bf((x1 * c - x2 * sn) * qs);
          out[(size_t)(rowb + r2) * N + colb + ii + 32] = f2bf((x2 * c + x1 * sn) * qs);
        }
      }
    }
  } else {
    // transposed+permuted write: vT[b][c][p(s)], p(s) consecutive over r
    const int bb = m0 >> 11;                   // batch (tile never straddles)
    #pragma unroll
    for (int i = 0; i < 4; ++i) {
      int rowb = m0 + wr * 64 + i * 16 + lg * 4;   // token, ≡0 mod 4
      int s = rowb & (SEQ - 1);
      int pbase = (s & ~31) + (((s & 15) >> 2) << 3) + (((s >> 4) & 1) << 2);
      #pragma unroll
      for (int j = 0; j < 4; ++j) {
        int c = n0 + wc * 64 + j * 16 + l15;
        u16x4 ov = { f2bf(acc[i][j][0]), f2bf(acc[i][j][1]),
                     f2bf(acc[i][j][2]), f2bf(acc[i][j][3]) };
        *(u16x4*)&out[(size_t)bb * SEQ * DIM + (size_t)c * SEQ + pbase] = ov;
      }
    }
  }
}

// ---------------- flash attention v13b (final: best verified config) ----------------
// QBLK=256: 256 blocks (XCD-swizzled), 512 thr / 8 waves; wave = 32 q-rows;
// KVB=64; 3-buf counted-vmcnt pipeline; launch_bounds(512,2) -> 16 waves/CU,
// VGPR 104, no spill. Attn is pinned at the LDS-BW wall (R21 TLP-doubling
// null; R10/R22 64-row-wave attempts both fail) — structural plateau.
#define KVB 64
__global__ __launch_bounds__(512, 2)
void attn_kernel(const u16* __restrict__ Q, const u16* __restrict__ Kb,
                 const u16* __restrict__ VT, u16* __restrict__ O) {
  __shared__ __align__(16) u16 Ks[3][KVB * 64];        // 8KB/buf
  __shared__ __align__(16) u16 Vs[3][HEAD_DIM * KVB];  // 16KB/buf

  const int tid = threadIdx.x, lane = tid & 63, wid = tid >> 6;   // wid 0..7
  int fl = blockIdx.x + 8 * (blockIdx.y + 16 * blockIdx.z);       // 256 blocks
  fl = (fl & 7) * 32 + (fl >> 3);                                 // XCD swizzle
  const int q0 = (fl & 7) * 256;
  const int h = (fl >> 3) & 15;
  const int b = fl >> 7;
  const int l15 = lane & 15, lg = lane >> 4;

  const u16* kbp = Kb + (size_t)(b * SEQ) * (HEADS * HALF) + h * HALF;
  const u16* vtb = VT + (size_t)b * SEQ * DIM + (size_t)(h * HEAD_DIM) * SEQ;

  // Q fragments (B-operand; col=l15, k=lg*8+j); wave owns rows q0+wid*32..+31
  bf16x8 qf[2][2];
  #pragma unroll
  for (int m = 0; m < 2; ++m)
    #pragma unroll
    for (int ks = 0; ks < 2; ++ks)
      qf[m][ks] = *(const bf16x8*)&Q[(size_t)(b * SEQ + q0 + wid * 32 + m * 16 + l15) * (HEADS * HALF)
                                     + h * HALF + ks * 32 + lg * 8];

  f32x4 o[2][8] = {};
  float l_part[2] = {0.f, 0.f};

  // staging geometry (both tiles: 128B rows, 8-row chunks, XOR-swizzled source)
  const int row8 = lane >> 3;
  const int colB = ((lane & 7) ^ row8) * 16;

  auto stage = [&](u16* KsD, u16* VsD, int kv0) {
    {                                        // K: 8 chunks of 8 kv-rows; wave w -> chunk w
      const u16* src = kbp + (size_t)(kv0 + wid * 8 + row8) * (HEADS * HALF) + (colB >> 1);
      async_copy16(src, KsD + wid * 512);
    }
    #pragma unroll
    for (int i = 0; i < 2; ++i) {            // V: 16 chunks of 8 d-rows; wave w -> {2w, 2w+1}
      int c = wid * 2 + i;
      const u16* src = vtb + (size_t)(c * 8 + row8) * SEQ + kv0 + (colB >> 1);
      async_copy16(src, VsD + c * 512);
    }
  };

  auto compute = [&](const u16* KsP, const u16* VsP) {
    const char* KsB = (const char*)KsP;
    const char* VsB = (const char*)VsP;
    const int kswz = (l15 & 7) << 4;
    // K fragments: kv = nf*16+l15 (4 nf groups), k = ks*32
    bf16x8 kf[2][4];
    #pragma unroll
    for (int ks = 0; ks < 2; ++ks)
      #pragma unroll
      for (int nf = 0; nf < 4; ++nf)
        kf[ks][nf] = *(const bf16x8*)(KsB + (nf * 16 + l15) * 128 + ((ks * 64 + lg * 16) ^ kswz));
    // swapped QK^T: S^T[kv][q]
    f32x4 s[2][4] = {};
    __builtin_amdgcn_s_setprio(1);
    #pragma unroll
    for (int ks = 0; ks < 2; ++ks)
      #pragma unroll
      for (int nf = 0; nf < 4; ++nf) {
        s[0][nf] = mfma16(kf[ks][nf], qf[0][ks], s[0][nf]);
        s[1][nf] = mfma16(kf[ks][nf], qf[1][ks], s[1][nf]);
      }
    __builtin_amdgcn_s_setprio(0);
    // PV in two 32-kv halves (register-P; V rows permuted per 32-block)
    #pragma unroll
    for (int ks2 = 0; ks2 < 2; ++ks2) {
      bf16x8 vf[8];
      #pragma unroll
      for (int db = 0; db < 8; ++db) {
        int row = db * 16 + l15;
        vf[db] = *(const bf16x8*)(VsB + row * 128 + ((ks2 * 64 + lg * 16) ^ ((row & 7) << 4)));
      }
      bf16x8 pa[2];
      #pragma unroll
      for (int m = 0; m < 2; ++m) {
        float p[8];
        #pragma unroll
        for (int nf2 = 0; nf2 < 2; ++nf2)
          #pragma unroll
          for (int r = 0; r < 4; ++r) {
            float v = EXP2F(s[m][ks2 * 2 + nf2][r]);
            p[nf2 * 4 + r] = v;
            l_part[m] += v;
          }
        union { uint32_t u[4]; bf16x8 v8; } pk;
        asm("v_cvt_pk_bf16_f32 %0, %1, %2" : "=v"(pk.u[0]) : "v"(p[0]), "v"(p[1]));
        asm("v_cvt_pk_bf16_f32 %0, %1, %2" : "=v"(pk.u[1]) : "v"(p[2]), "v"(p[3]));
        asm("v_cvt_pk_bf16_f32 %0, %1, %2" : "=v"(pk.u[2]) : "v"(p[4]), "v"(p[5]));
        asm("v_cvt_pk_bf16_f32 %0, %1, %2" : "=v"(pk.u[3]) : "v"(p[6]), "v"(p[7]));
        pa[m] = pk.v8;
      }
      __builtin_amdgcn_s_setprio(1);
      #pragma unroll
      for (int db = 0; db < 8; ++db) {
        o[0][db] = mfma16(pa[0], vf[db], o[0][db]);
        o[1][db] = mfma16(pa[1], vf[db], o[1][db]);
      }
      __builtin_amdgcn_s_setprio(0);
    }
  };

#define WAIT3 asm volatile("s_waitcnt vmcnt(3)" ::: "memory")
#define WAIT0 asm volatile("s_waitcnt vmcnt(0)" ::: "memory")
#define BAR   __builtin_amdgcn_s_barrier()

  // prologue (3 loads/thread per stage; 2 stages in flight -> wait older 3)
  stage(Ks[0], Vs[0], 0);
  stage(Ks[1], Vs[1], KVB);
  WAIT3; BAR;
  // main: NT=32; t = 0..29 in 10 triples (static buffers, counted waits)
  int t = 0;
  for (int i = 0; i < 10; ++i) {
    stage(Ks[2], Vs[2], (t + 2) * KVB); compute(Ks[0], Vs[0]); WAIT3; BAR;
    stage(Ks[0], Vs[0], (t + 3) * KVB); compute(Ks[1], Vs[1]); WAIT3; BAR;
    stage(Ks[1], Vs[1], (t + 4) * KVB); compute(Ks[2], Vs[2]); WAIT3; BAR;
    t += 3;
  }
  // tail: t = 30, 31
  compute(Ks[0], Vs[0]); WAIT0; BAR;
  compute(Ks[1], Vs[1]);

#undef WAIT3
#undef WAIT0
#undef BAR

  // deferred row-sum: lane holds partial for q=m*16+l15 over kv=lg-chunk
  #pragma unroll
  for (int m = 0; m < 2; ++m) {
    float l = l_part[m];
    l += __shfl_xor(l, 16);
    l += __shfl_xor(l, 32);
    float inv[4];
    #pragma unroll
    for (int r = 0; r < 4; ++r)
      inv[r] = 1.0f / __shfl(l, lg * 4 + r);
    #pragma unroll
    for (int db = 0; db < 8; ++db)
      #pragma unroll
      for (int r = 0; r < 4; ++r) {
        int row = q0 + wid * 32 + m * 16 + lg * 4 + r;
        O[(size_t)(b * SEQ + row) * DIM + h * HEAD_DIM + db * 16 + l15] = f2bf(o[m][db][r] * inv[r]);
      }
  }
}

// ---------------- host ----------------
extern "C" void kernel_launch(void* const* d_in, const int* in_sizes, int n_in,
                              void* d_out, int out_size, void* d_ws, size_t ws_size,
                              hipStream_t stream) {
  const float* x     = (const float*)d_in[0];
  const float* wq_d  = (const float*)d_in[1];
  const float* wkv_d = (const float*)d_in[2];
  const float* wq_u  = (const float*)d_in[3];
  const float* wk_u  = (const float*)d_in[4];
  const float* wv_u  = (const float*)d_in[5];
  const float* wo    = (const float*)d_in[6];

  char* ws = (char*)d_ws;
  size_t off = 0;
  auto alloc = [&](size_t bytes) -> void* {
    void* p = ws + off;
    off += (bytes + 255) & ~(size_t)255;
    return p;
  };
  u16* wdT    = (u16*)alloc((size_t)512 * DIM * 2);
  u16* wquT   = (u16*)alloc((size_t)1024 * LATENT * 2);
  u16* wkuT   = (u16*)alloc((size_t)1024 * LATENT * 2);
  u16* wvuT   = (u16*)alloc((size_t)DIM * LATENT * 2);
  u16* woT    = (u16*)alloc((size_t)DIM * DIM * 2);
  u16* lat    = (u16*)alloc((size_t)TOK * 512 * 2);
  u16* latP   = (u16*)alloc((size_t)4 * TOK * 512 * 2);   // split-K4 bf16 partials
  u16* qb     = (u16*)alloc((size_t)TOK * 1024 * 2);
  u16* kb     = (u16*)alloc((size_t)TOK * 1024 * 2);
  u16* vT     = (u16*)alloc((size_t)TOK * DIM * 2);
  u16* ao     = (u16*)alloc((size_t)TOK * DIM * 2);
  float* ct   = (float*)alloc((size_t)SEQ * 32 * 4);
  float* st   = (float*)alloc((size_t)SEQ * 32 * 4);
  (void)in_sizes; (void)n_in; (void)out_size; (void)ws_size;

  // fused prep: all weight transposes + rope tables in one launch
  prep_k<<<dim3(6400), dim3(32, 8), 0, stream>>>(wq_d, wkv_d, wq_u, wk_u, wv_u, wo,
                                                 wdT, wquT, wkuT, wvuT, woT, ct, st);

  // lat partials = x @ [wq_d|wkv_d]: fp32 A reg-staged, split-K4, bf16 partials
  gemm_lat<<<dim3(4, 32, 4), 256, 0, stream>>>(x, DIM, wdT, DIM, latP, TOK, 512, 512);
  // reduce once to bf16 lat (fp32 accumulate of 4 bf16 slabs)
  combine_bf<<<(TOK * 512 / 8 + 255) / 256, 256, 0, stream>>>(latP, lat, TOK * 512 / 8, (size_t)TOK * 512);

  // merged q/k/v up-proj (3-buf counted-vmcnt pipeline)
  upproj_k<<<dim3(1024), 256, 0, stream>>>(lat, wquT, wkuT, wvuT, qb, kb, vT, ct, st);

  // attention: QBLK=256, KVB=64, 8 waves/block, 256 blocks (2 blocks/CU)
  attn_kernel<<<dim3(SEQ / 256, HEADS, BATCH), 512, 0, stream>>>(qb, kb, vT, ao);

  // out = attn_out @ wo — 3-buf counted-vmcnt pipelined GEMM, fp32 direct
  gemm_wo<<<dim3(16, 32), 256, 0, stream>>>(ao, woT, (float*)d_out);
}